// Round 1
// baseline (433.574 us; speedup 1.0000x reference)
//
#include <hip/hip_runtime.h>

// Problem constants (from reference): x [N=8, C=64, D=16, H=128, W=128] f32,
// bias [64] f32. out = tanh(softmax_C(mean_D(x) + bias)) * 2, f32 [N,C,H,W].
constexpr int C  = 64;
constexpr int D  = 16;
constexpr int HW = 128 * 128;
constexpr float SCALING = 2.0f;

// One thread per (n, h, w) output column. Lane i handles spatial s+i ->
// every global load/store is a contiguous 256B wave transaction.
// 64 logits live in registers (loops fully unrolled -> static indexing).
__global__ __launch_bounds__(256) void fused_mean_softmax_tanh(
    const float* __restrict__ x,
    const float* __restrict__ bias,
    float* __restrict__ out)
{
    const int idx = blockIdx.x * 256 + threadIdx.x;   // 0 .. N*HW-1
    const int n = idx >> 14;                          // idx / HW  (HW = 2^14)
    const int s = idx & (HW - 1);                     // idx % HW

    const float* px = x + (size_t)n * C * D * HW + s;

    float logit[C];

    // Mean over depth: 16 loads per channel, 4-way split accumulators for ILP.
    #pragma unroll
    for (int c = 0; c < C; ++c) {
        const float* p = px + (size_t)c * D * HW;
        float a0 = 0.f, a1 = 0.f, a2 = 0.f, a3 = 0.f;
        #pragma unroll
        for (int d = 0; d < D; d += 4) {
            a0 += p[(size_t)(d + 0) * HW];
            a1 += p[(size_t)(d + 1) * HW];
            a2 += p[(size_t)(d + 2) * HW];
            a3 += p[(size_t)(d + 3) * HW];
        }
        logit[c] = (a0 + a1) + (a2 + a3);
    }

    // + bias (uniform address -> scalar loads, L1/K$-cached)
    #pragma unroll
    for (int c = 0; c < C; ++c)
        logit[c] = logit[c] * (1.0f / D) + bias[c];

    // Numerically-stable softmax over the 64 in-register channels.
    float m = logit[0];
    #pragma unroll
    for (int c = 1; c < C; ++c) m = fmaxf(m, logit[c]);

    float sum = 0.f;
    #pragma unroll
    for (int c = 0; c < C; ++c) {
        logit[c] = __expf(logit[c] - m);
        sum += logit[c];
    }
    const float inv = 1.0f / sum;

    // tanh(p) * 2, coalesced strided stores (one 256B wave store per channel).
    float* po = out + (size_t)n * C * HW + s;
    #pragma unroll
    for (int c = 0; c < C; ++c) {
        const float p = logit[c] * inv;
        po[(size_t)c * HW] = SCALING * tanhf(p);
    }
}

extern "C" void kernel_launch(void* const* d_in, const int* in_sizes, int n_in,
                              void* d_out, int out_size, void* d_ws, size_t ws_size,
                              hipStream_t stream)
{
    const float* x    = (const float*)d_in[0];
    const float* bias = (const float*)d_in[1];
    float* out        = (float*)d_out;

    const int N     = in_sizes[0] / (C * D * HW);   // = 8
    const int total = N * HW;                       // 131072 threads
    fused_mean_softmax_tanh<<<total / 256, 256, 0, stream>>>(x, bias, out);
}

// Round 2
// 121.892 us; speedup vs baseline: 3.5570x; 3.5570x over previous
//
#include <hip/hip_runtime.h>

// x [N=8, C=64, D=16, H=128, W=128] f32, bias [64] f32.
// out = tanh(softmax_C(mean_D(x) + bias)) * 2, f32 [N,C,H,W].
constexpr int C   = 64;
constexpr int D   = 16;
constexpr int HW  = 128 * 128;
constexpr int HW4 = HW / 4;
constexpr float SCALING = 2.0f;

__device__ inline void add4(float4& a, const float4& b) {
    a.x += b.x; a.y += b.y; a.z += b.z; a.w += b.w;
}

// ---------- Pass 1: mean over depth (pure streaming, float4) ----------
// One thread per 4 output elems. t = (n*C + c)*HW4 + q. Reads 16 strided
// float4 (64KB stride), fully unrolled -> 16 loads in flight per thread.
__global__ __launch_bounds__(256) void mean_depth(
    const float4* __restrict__ x, float4* __restrict__ m)
{
    const int t  = blockIdx.x * 256 + threadIdx.x;       // 0 .. N*C*HW4-1
    const int nc = t / HW4;
    const int q  = t - nc * HW4;
    const float4* p = x + (size_t)nc * (D * HW4) + q;

    float4 a0 = {0,0,0,0}, a1 = a0, a2 = a0, a3 = a0;
    #pragma unroll
    for (int d = 0; d < D; d += 4) {
        float4 v0 = p[(size_t)(d + 0) * HW4];
        float4 v1 = p[(size_t)(d + 1) * HW4];
        float4 v2 = p[(size_t)(d + 2) * HW4];
        float4 v3 = p[(size_t)(d + 3) * HW4];
        add4(a0, v0); add4(a1, v1); add4(a2, v2); add4(a3, v3);
    }
    add4(a0, a1); add4(a2, a3); add4(a0, a2);
    m[t] = a0;    // raw sum; 1/D folded into pass 2
}

// ---------- Pass 2: channel softmax + tanh, logits in registers ----------
__global__ __launch_bounds__(256, 2) void softmax_tanh(
    const float* __restrict__ m, const float* __restrict__ bias,
    float* __restrict__ out)
{
    const int t = blockIdx.x * 256 + threadIdx.x;        // 0 .. N*HW-1
    const int n = t >> 14;
    const int s = t & (HW - 1);

    const float* pm = m + (size_t)n * C * HW + s;

    float logit[C];
    #pragma unroll
    for (int c = 0; c < C; ++c) logit[c] = pm[(size_t)c * HW];

    #pragma unroll
    for (int c = 0; c < C; ++c) logit[c] = logit[c] * (1.0f / D) + bias[c];

    float mx = logit[0];
    #pragma unroll
    for (int c = 1; c < C; ++c) mx = fmaxf(mx, logit[c]);

    float sum = 0.f;
    #pragma unroll
    for (int c = 0; c < C; ++c) {
        logit[c] = __expf(logit[c] - mx);
        sum += logit[c];
    }
    const float inv = 1.0f / sum;

    float* po = out + (size_t)n * C * HW + s;
    #pragma unroll
    for (int c = 0; c < C; ++c) {
        const float p = logit[c] * inv;            // in (0, 1]
        const float e = __expf(2.0f * p);          // tanh(p) = 1 - 2/(e^{2p}+1)
        po[(size_t)c * HW] = SCALING * (1.0f - 2.0f / (e + 1.0f));
    }
}

// ---------- Fallback: fused single kernel (if ws too small) ----------
__global__ __launch_bounds__(256, 2) void fused_fallback(
    const float* __restrict__ x, const float* __restrict__ bias,
    float* __restrict__ out)
{
    const int idx = blockIdx.x * 256 + threadIdx.x;
    const int n = idx >> 14;
    const int s = idx & (HW - 1);
    const float* px = x + (size_t)n * C * D * HW + s;

    float logit[C];
    #pragma unroll
    for (int c = 0; c < C; ++c) {
        const float* p = px + (size_t)c * D * HW;
        float a0 = 0.f, a1 = 0.f, a2 = 0.f, a3 = 0.f;
        #pragma unroll
        for (int d = 0; d < D; d += 4) {
            a0 += p[(size_t)(d + 0) * HW];
            a1 += p[(size_t)(d + 1) * HW];
            a2 += p[(size_t)(d + 2) * HW];
            a3 += p[(size_t)(d + 3) * HW];
        }
        logit[c] = ((a0 + a1) + (a2 + a3)) * (1.0f / D) + bias[c];
    }
    float mx = logit[0];
    #pragma unroll
    for (int c = 1; c < C; ++c) mx = fmaxf(mx, logit[c]);
    float sum = 0.f;
    #pragma unroll
    for (int c = 0; c < C; ++c) { logit[c] = __expf(logit[c] - mx); sum += logit[c]; }
    const float inv = 1.0f / sum;
    float* po = out + (size_t)n * C * HW + s;
    #pragma unroll
    for (int c = 0; c < C; ++c) {
        const float p = logit[c] * inv;
        const float e = __expf(2.0f * p);
        po[(size_t)c * HW] = SCALING * (1.0f - 2.0f / (e + 1.0f));
    }
}

extern "C" void kernel_launch(void* const* d_in, const int* in_sizes, int n_in,
                              void* d_out, int out_size, void* d_ws, size_t ws_size,
                              hipStream_t stream)
{
    const float* x    = (const float*)d_in[0];
    const float* bias = (const float*)d_in[1];
    float* out        = (float*)d_out;

    const int N = in_sizes[0] / (C * D * HW);            // = 8
    const size_t ws_needed = (size_t)N * C * HW * sizeof(float);  // 33.5 MB

    if (ws_size >= ws_needed) {
        float* mean_ws = (float*)d_ws;
        const int t1 = N * C * HW4;                      // 2,097,152
        mean_depth<<<t1 / 256, 256, 0, stream>>>(
            (const float4*)x, (float4*)mean_ws);
        const int t2 = N * HW;                           // 131,072
        softmax_tanh<<<t2 / 256, 256, 0, stream>>>(mean_ws, bias, out);
    } else {
        const int t = N * HW;
        fused_fallback<<<t / 256, 256, 0, stream>>>(x, bias, out);
    }
}